// Round 1
// baseline (329.963 us; speedup 1.0000x reference)
//
#include <hip/hip_runtime.h>
#include <float.h>

#define CC 256
#define HH 200
#define WW 320
#define MM 14
#define SPAN_MAX 144

__global__ void roi_init(float* __restrict__ binmax) {
    int t = blockIdx.x * blockDim.x + threadIdx.x;
    if (t < MM * MM) binmax[t] = -FLT_MAX;
}

__device__ inline void atomicMaxF(float* addr, float val) {
    // Ordered-int trick: valid for finite floats.
    if (val >= 0.0f) {
        atomicMax((int*)addr, __float_as_int(val));
    } else {
        atomicMin((unsigned int*)addr, __float_as_uint(val));
    }
}

__global__ __launch_bounds__(256) void roi_reduce(
    const float* __restrict__ feature,
    const float* __restrict__ rois,
    float* __restrict__ binmax)
{
    const int bid = blockIdx.x;
    const int r = bid / MM;
    const int m = bid - r * MM;
    const int tid = threadIdx.x;

    const float ry1 = rois[r * 4 + 0];
    const float rx1 = rois[r * 4 + 1];
    const float ry2 = rois[r * 4 + 2];
    const float rx2 = rois[r * 4 + 3];
    const float sh = (ry2 - ry1) * (1.0f / 14.0f);
    const float sw = (rx2 - rx1) * (1.0f / 14.0f);
    const float f13 = 1.0f / 3.0f, f23 = 2.0f / 3.0f;

    // Two y sample coords for this bin-row m (reference clamp semantics).
    const float yA = ry1 + sh * (float)m + sh * f13;
    const float yB = ry1 + sh * (float)m + sh * f23;
    const int y1A = min(max((int)floorf(yA), 0), HH - 1);
    const int y2A = min(max((int)floorf(yA) + 1, 0), HH - 1);
    const int y1B = min(max((int)floorf(yB), 0), HH - 1);
    const int y2B = min(max((int)floorf(yB) + 1, 0), HH - 1);
    const float wyloA = yA - (float)y1A, wyhiA = (float)y2A - yA;
    const float wyloB = yB - (float)y1B, wyhiB = (float)y2B - yB;

    // Column window covering all 28 x sample points' corners.
    const float xmin = rx1 + sw * f13;
    const float xmax = rx1 + sw * 13.0f + sw * f23;
    int xlo = min(max((int)floorf(xmin), 0), WW - 1);
    int xhi = min(max((int)floorf(xmax) + 1, 0), WW - 1);
    int span = xhi - xlo + 1;
    if (span > SPAN_MAX) span = SPAN_MAX;  // cannot trigger with given input bounds

    // Compute-thread mapping: tid = s + 56*cs ; s = n*4 + j*2 + i
    const int s  = tid % 56;
    const int cs = tid / 56;        // channel sub-index 0..3 (cs==4 -> loader-only)
    const int n  = s >> 2;
    const int j  = (s >> 1) & 1;
    const int i  = s & 1;
    const bool active = (tid < 224);

    float wxlo = 0.f, wxhi = 0.f, wylo = 0.f, wyhi = 0.f;
    int c0 = 0, c1 = 0, ra = 0, rb = 1;
    if (active) {
        float x = rx1 + sw * (float)n + sw * (j ? f23 : f13);
        int x1c = min(max((int)floorf(x), 0), WW - 1);
        int x2c = min(max((int)floorf(x) + 1, 0), WW - 1);
        wxlo = x - (float)x1c;
        wxhi = (float)x2c - x;
        c0 = min(max(x1c - xlo, 0), span - 1);
        c1 = min(max(x2c - xlo, 0), span - 1);
        if (i == 0) { ra = 0; rb = 1; wylo = wyloA; wyhi = wyhiA; }
        else        { ra = 2; rb = 3; wylo = wyloB; wyhi = wyhiB; }
    }

    __shared__ float tile[4][4][SPAN_MAX];  // [ch_sub][row][col] 9216 B
    __shared__ float pmax[224];

    // Loader mapping: 4 groups of 64 lanes, one feature row each.
    const int rg   = tid >> 6;
    const int lane = tid & 63;
    const int myrow = (rg == 0) ? y1A : (rg == 1) ? y2A : (rg == 2) ? y1B : y2B;
    const int rowoff = myrow * WW + xlo;

    float lmax = -FLT_MAX;

    for (int cc = 0; cc < CC; cc += 4) {
        __syncthreads();
        #pragma unroll
        for (int ch = 0; ch < 4; ++ch) {
            const float* src = feature + (cc + ch) * (HH * WW) + rowoff;
            for (int col = lane; col < span; col += 64)
                tile[ch][rg][col] = src[col];
        }
        __syncthreads();
        if (active) {
            float v11 = tile[cs][ra][c0];
            float v12 = tile[cs][ra][c1];
            float v21 = tile[cs][rb][c0];
            float v22 = tile[cs][rb][c1];
            float p = v11 * wxhi + v12 * wxlo;
            float q = v21 * wxhi + v22 * wxlo;
            lmax = fmaxf(lmax, p * wyhi + q * wylo);
        }
    }

    if (active) pmax[tid] = lmax;
    __syncthreads();
    if (tid < MM) {  // one thread per bin n
        float v = -FLT_MAX;
        #pragma unroll
        for (int c4 = 0; c4 < 4; ++c4)
            #pragma unroll
            for (int q4 = 0; q4 < 4; ++q4)
                v = fmaxf(v, pmax[c4 * 56 + tid * 4 + q4]);
        atomicMaxF(&binmax[m * MM + tid], v);
    }
}

__global__ __launch_bounds__(256) void roi_bcast(
    const float* __restrict__ binmax, float4* __restrict__ out, int total4)
{
    __shared__ float4 b4[49];  // 196 floats = 49 float4, aligned with bin period
    int t = threadIdx.x;
    if (t < 49) b4[t] = ((const float4*)binmax)[t];
    __syncthreads();
    int idx = blockIdx.x * 256 + t;
    if (idx < total4) out[idx] = b4[idx % 49];
}

extern "C" void kernel_launch(void* const* d_in, const int* in_sizes, int n_in,
                              void* d_out, int out_size, void* d_ws, size_t ws_size,
                              hipStream_t stream) {
    const float* feature = (const float*)d_in[0];
    const float* rois    = (const float*)d_in[1];
    float* binmax = (float*)d_ws;
    float* out    = (float*)d_out;

    const int R = in_sizes[1] / 4;

    roi_init<<<1, 256, 0, stream>>>(binmax);
    roi_reduce<<<R * MM, 256, 0, stream>>>(feature, rois, binmax);

    const int total4 = out_size / 4;
    roi_bcast<<<(total4 + 255) / 256, 256, 0, stream>>>(binmax, (float4*)out, total4);
}

// Round 2
// 145.105 us; speedup vs baseline: 2.2740x; 2.2740x over previous
//
#include <hip/hip_runtime.h>
#include <float.h>

#define CC 256
#define HH 200
#define WW 320
#define HW (HH * WW)
#define MM 14
#define SPAN_MAX 144
#define SPAN_PAD 145
#define NCH 8            // channels staged per barrier round
#define CG 4             // channel-group blocks per (roi, bin-row)
#define CPB (CC / CG)    // 64 channels per block

__global__ void roi_init(float* __restrict__ binmax) {
    int t = blockIdx.x * blockDim.x + threadIdx.x;
    if (t < MM * MM) binmax[t] = -FLT_MAX;
}

__device__ inline void atomicMaxF(float* addr, float val) {
    // Ordered-int trick: valid for finite floats; positive path can never be
    // overridden by the negative path (uint-min keeps positive patterns).
    if (val >= 0.0f) {
        atomicMax((int*)addr, __float_as_int(val));
    } else {
        atomicMin((unsigned int*)addr, __float_as_uint(val));
    }
}

__global__ __launch_bounds__(256, 8) void roi_reduce(
    const float* __restrict__ feature,
    const float* __restrict__ rois,
    float* __restrict__ binmax)
{
    const int bid = blockIdx.x;
    const int cg  = bid & (CG - 1);
    const int rm  = bid >> 2;          // CG == 4
    const int m   = rm % MM;
    const int r   = rm / MM;
    const int tid = threadIdx.x;
    const int cbase = cg * CPB;

    const float ry1 = rois[r * 4 + 0];
    const float rx1 = rois[r * 4 + 1];
    const float ry2 = rois[r * 4 + 2];
    const float rx2 = rois[r * 4 + 3];
    const float sh = (ry2 - ry1) * (1.0f / 14.0f);
    const float sw = (rx2 - rx1) * (1.0f / 14.0f);
    const float f13 = 1.0f / 3.0f, f23 = 2.0f / 3.0f;

    // Two y sample coords for this bin-row m (reference clamp semantics).
    const float yA = ry1 + sh * (float)m + sh * f13;
    const float yB = ry1 + sh * (float)m + sh * f23;
    const int y1A = min(max((int)floorf(yA), 0), HH - 1);
    const int y2A = min(max((int)floorf(yA) + 1, 0), HH - 1);
    const int y1B = min(max((int)floorf(yB), 0), HH - 1);
    const int y2B = min(max((int)floorf(yB) + 1, 0), HH - 1);
    const float wyloA = yA - (float)y1A, wyhiA = (float)y2A - yA;
    const float wyloB = yB - (float)y1B, wyhiB = (float)y2B - yB;

    // Column window covering all 28 x sample points' corners.
    const float xmin = rx1 + sw * f13;
    const float xmax = rx1 + sw * 13.0f + sw * f23;
    int xlo = min(max((int)floorf(xmin), 0), WW - 1);
    int xhi = min(max((int)floorf(xmax) + 1, 0), WW - 1);
    int span = xhi - xlo + 1;
    if (span > SPAN_MAX) span = SPAN_MAX;  // cannot trigger with given input bounds

    // Compute-thread mapping: tid = s + 56*cs ; s = n*4 + j*2 + i
    const int s  = tid % 56;
    const int cs = tid / 56;        // channel sub-index 0..3 (tid>=224 -> loader-only)
    const int n  = s >> 2;
    const int j  = (s >> 1) & 1;
    const int i  = s & 1;
    const bool active = (tid < 224);

    float wxlo = 0.f, wxhi = 0.f, wylo = 0.f, wyhi = 0.f;
    int c0 = 0, c1 = 0, ra = 0, rb = 1;
    if (active) {
        float x = rx1 + sw * (float)n + sw * (j ? f23 : f13);
        int x1c = min(max((int)floorf(x), 0), WW - 1);
        int x2c = min(max((int)floorf(x) + 1, 0), WW - 1);
        wxlo = x - (float)x1c;
        wxhi = (float)x2c - x;
        c0 = min(max(x1c - xlo, 0), span - 1);
        c1 = min(max(x2c - xlo, 0), span - 1);
        if (i == 0) { ra = 0; rb = 1; wylo = wyloA; wyhi = wyhiA; }
        else        { ra = 2; rb = 3; wylo = wyloB; wyhi = wyhiB; }
    }

    __shared__ float tile[NCH][4][SPAN_PAD];  // 18.56 KB
    __shared__ float pmax[224];

    // Loader mapping: 4 groups of 64 lanes, one feature row each.
    const int rg   = tid >> 6;
    const int lane = tid & 63;
    const int myrow = (rg == 0) ? y1A : (rg == 1) ? y2A : (rg == 2) ? y1B : y2B;
    const int rowoff = myrow * WW + xlo;

    float lmax = -FLT_MAX;

    for (int cc = 0; cc < CPB; cc += NCH) {
        const float* src = feature + (cbase + cc) * HW + rowoff;
        __syncthreads();   // tile safe to overwrite (readers of prev round done)
        // Issue all NCH loads per column step before any LDS write: keeps
        // NCH independent global loads in flight per lane.
        for (int col = lane; col < span; col += 64) {
            float tmp[NCH];
            #pragma unroll
            for (int ch = 0; ch < NCH; ++ch) tmp[ch] = src[ch * HW + col];
            #pragma unroll
            for (int ch = 0; ch < NCH; ++ch) tile[ch][rg][col] = tmp[ch];
        }
        __syncthreads();
        if (active) {
            #pragma unroll
            for (int q = 0; q < 2; ++q) {
                const int ch = cs * 2 + q;
                float v11 = tile[ch][ra][c0];
                float v12 = tile[ch][ra][c1];
                float v21 = tile[ch][rb][c0];
                float v22 = tile[ch][rb][c1];
                float p = v11 * wxhi + v12 * wxlo;
                float q2 = v21 * wxhi + v22 * wxlo;
                lmax = fmaxf(lmax, p * wyhi + q2 * wylo);
            }
        }
    }

    if (active) pmax[tid] = lmax;
    __syncthreads();
    if (tid < MM) {  // one thread per bin n
        float v = -FLT_MAX;
        #pragma unroll
        for (int c4 = 0; c4 < 4; ++c4)
            #pragma unroll
            for (int q4 = 0; q4 < 4; ++q4)
                v = fmaxf(v, pmax[c4 * 56 + tid * 4 + q4]);
        atomicMaxF(&binmax[m * MM + tid], v);
    }
}

__global__ __launch_bounds__(256) void roi_bcast(
    const float* __restrict__ binmax, float4* __restrict__ out, int total4)
{
    __shared__ float4 b4[49];  // 196 floats = 49 float4, aligned with bin period
    int t = threadIdx.x;
    if (t < 49) b4[t] = ((const float4*)binmax)[t];
    __syncthreads();
    int idx = blockIdx.x * 256 + t;
    if (idx < total4) out[idx] = b4[idx % 49];
}

extern "C" void kernel_launch(void* const* d_in, const int* in_sizes, int n_in,
                              void* d_out, int out_size, void* d_ws, size_t ws_size,
                              hipStream_t stream) {
    const float* feature = (const float*)d_in[0];
    const float* rois    = (const float*)d_in[1];
    float* binmax = (float*)d_ws;
    float* out    = (float*)d_out;

    const int R = in_sizes[1] / 4;

    roi_init<<<1, 256, 0, stream>>>(binmax);
    roi_reduce<<<R * MM * CG, 256, 0, stream>>>(feature, rois, binmax);

    const int total4 = out_size / 4;
    roi_bcast<<<(total4 + 255) / 256, 256, 0, stream>>>(binmax, (float4*)out, total4);
}